// Round 16
// baseline (129.944 us; speedup 1.0000x reference)
//
#include <hip/hip_runtime.h>
#include <stdint.h>

// ---------------------------------------------------------------------------
// ManifoldAugmentation: x (8192,256) fp32 ->
//   out = concat([x, (1-alpha)*x + alpha*x[sel]]) (16384,256) fp32
// Stage 1: bf16 MFMA GEMM, fragment-linear xbf (r12-proven), m=2 / 512 thr
//          (16 waves/CU, r12-proven) + wave-local scan (r15-proven): wave w
//          scans its own 32 rows -> skeys single-buffered, no cross-wave dep.
//          256-col chunks -> grid 1024, 3 blocks/CU resident. 192 cand/row.
// Stage 2: fp32 rescore of top-16 of 192 (4-lane-group coalesced dot),
//          constexpr threefry key folding.
// PRNG: JAX threefry, partitionable semantics (verified PASS rounds 4-15).
// ---------------------------------------------------------------------------

#define NROWS 8192
#define ND4   64

typedef __attribute__((ext_vector_type(8))) short bf16x8;
typedef __attribute__((ext_vector_type(4))) float f32x4;

__device__ __forceinline__ uint32_t umin32(uint32_t a, uint32_t b) { return a < b ? a : b; }
__device__ __forceinline__ uint32_t umax32(uint32_t a, uint32_t b) { return a > b ? a : b; }

__device__ __forceinline__ uint32_t pkmin16(uint32_t a, uint32_t b) {
  uint32_t r;
  asm("v_pk_min_u16 %0, %1, %2" : "=v"(r) : "v"(a), "v"(b));
  return r;
}
__device__ __forceinline__ uint32_t pkmax16(uint32_t a, uint32_t b) {
  uint32_t r;
  asm("v_pk_max_u16 %0, %1, %2" : "=v"(r) : "v"(a), "v"(b));
  return r;
}

// ------------------------- threefry2x32 (20 rounds) ------------------------
__device__ __forceinline__ uint32_t rotl32(uint32_t v, int d) {
  return (v << d) | (v >> (32 - d));
}

#define TFBODY(k0, k1)                                                        \
  const uint32_t ks2 = (k0) ^ (k1) ^ 0x1BD11BDAu;                             \
  x0 += (k0); x1 += (k1);                                                     \
  TFR(13) TFR(15) TFR(26) TFR(6)                                              \
  x0 += (k1);  x1 += ks2 + 1u;                                                \
  TFR(17) TFR(29) TFR(16) TFR(24)                                             \
  x0 += ks2; x1 += (k0) + 2u;                                                 \
  TFR(13) TFR(15) TFR(26) TFR(6)                                              \
  x0 += (k0);  x1 += (k1) + 3u;                                               \
  TFR(17) TFR(29) TFR(16) TFR(24)                                             \
  x0 += (k1);  x1 += ks2 + 4u;                                                \
  TFR(13) TFR(15) TFR(26) TFR(6)                                              \
  x0 += ks2; x1 += (k0) + 5u;

__device__ __forceinline__ void tf2x32(uint32_t k0, uint32_t k1,
                                       uint32_t& x0, uint32_t& x1) {
#define TFR(R) { x0 += x1; x1 = rotl32(x1, R); x1 ^= x0; }
  TFBODY(k0, k1)
#undef TFR
}

// compile-time threefry (identical math) for constant key derivation
struct U2 { uint32_t x, y; };
constexpr uint32_t crotl(uint32_t v, int d) {
  return (v << d) | (v >> (32 - d));
}
constexpr U2 tfc(uint32_t k0, uint32_t k1, uint32_t x0, uint32_t x1) {
#define TFR(R) { x0 += x1; x1 = crotl(x1, R); x1 ^= x0; }
  TFBODY(k0, k1)
#undef TFR
  return U2{x0, x1};
}
// rng = fold_in(key(42),0); kc,ka = split(rng); k1,k2 = split(kc)
constexpr U2 RG = tfc(0u, 42u, 0u, 0u);
constexpr U2 KC = tfc(RG.x, RG.y, 0u, 0u);
constexpr U2 KA = tfc(RG.x, RG.y, 0u, 1u);
constexpr U2 K1 = tfc(KC.x, KC.y, 0u, 0u);
constexpr U2 K2 = tfc(KC.x, KC.y, 0u, 1u);

// --------------------- top-6 (val,idx) lexicographic (fp32 stage) ----------
__device__ __forceinline__ bool lessp(float a, int ai, float b, int bi) {
  return (a < b) || ((a == b) && (ai < bi));
}

__device__ __forceinline__ void insert6(float key, int idx,
                                        float (&v)[6], int (&ix)[6]) {
  if (!lessp(key, idx, v[5], ix[5])) return;
#pragma unroll
  for (int j = 5; j >= 1; --j) {
    if (lessp(key, idx, v[j - 1], ix[j - 1])) {
      v[j] = v[j - 1]; ix[j] = ix[j - 1];
    } else {
      v[j] = key; ix[j] = idx; return;
    }
  }
  v[0] = key; ix[0] = idx;
}

// ----------------------------- small helpers -------------------------------
__device__ __forceinline__ unsigned short f2bf(float f) {
  uint32_t u = __float_as_uint(f);
  u += 0x7FFFu + ((u >> 16) & 1u);          // RNE
  return (unsigned short)(u >> 16);
}

__device__ __forceinline__ void gload_lds16(const void* g, void* l) {
  __builtin_amdgcn_global_load_lds(
      (const __attribute__((address_space(1))) unsigned int*)g,
      (__attribute__((address_space(3))) unsigned int*)l, 16, 0, 0);
}

// ------------------------------ kernel 1: prep -----------------------------
// sq (round-4 exact reduce) + bf16 convert into FRAGMENT-LINEAR layout (r12).
__global__ void prep_kernel(const float* __restrict__ x,
                            float* __restrict__ sq,
                            unsigned short* __restrict__ xbf) {
  int row  = blockIdx.x * 4 + (threadIdx.x >> 6);
  int lane = threadIdx.x & 63;
  const float4* xv4 = reinterpret_cast<const float4*>(x);
  float4 vv = xv4[(size_t)row * ND4 + lane];
  float t = vv.x * vv.x + vv.y * vv.y + vv.z * vv.z + vv.w * vv.w;
#pragma unroll
  for (int off = 32; off >= 1; off >>= 1) t += __shfl_down(t, off);
  if (lane == 0) sq[row] = t;
  ushort4 st;
  st.x = f2bf(vv.x); st.y = f2bf(vv.y); st.z = f2bf(vv.z); st.w = f2bf(vv.w);
  int T = row >> 5, h = (row >> 4) & 1, c = row & 15;
  int kb = lane >> 3, g = (lane >> 1) & 3, half8 = lane & 1;
  size_t f = ((size_t)(T * 8 + kb) * 2 + h) * 64 + g * 16 + c;
  *reinterpret_cast<ushort4*>(xbf + f * 8 + half8 * 4) = st;
}

// --------------------------- kernel 2: gemm+topk ---------------------------
// grid 1024 = 32 row-blocks (256 rows) x 32 col-chunks (256 cols); 512 thr.
// 8 waves x 32-row stripes (m=2); B-tile (32 cols, 16KB) contiguous-staged,
// double-buffered; B ds_read_b128 lane-linear. skeys single-buffered: wave w
// writes AND scans its own rows (lane-pair per row) -> no barrier on skeys;
// one barrier/tile for the B buffer. v_pk sorted-6; end: unpack + lane-pair
// merge -> exact per-(row,chunk) top-6 -> 192 cand/row.
__global__ __launch_bounds__(512, 6)
void gemm_topk_kernel(const unsigned short* __restrict__ xbf,
                      const float* __restrict__ sq,
                      uint32_t* __restrict__ cand) {
  __shared__ __align__(16) char smem[49216];  // 2x16KB B + 16448B skeys
  uint32_t* skeys = reinterpret_cast<uint32_t*>(smem + 32768);

  const int tid = threadIdx.x;
  const int bid = blockIdx.x;
  const int rowblk = bid & 31;
  const int chunk  = bid >> 5;          // 0..31
  const int rowbase = rowblk * 256;
  const int colbase = chunk * 256;
  const int w = tid >> 6;
  const int l = tid & 63;
  const int g = l >> 4;
  const int c = l & 15;

  // A fragments: rows rowbase + w*32 + m*16 + c -> T=rowblk*8+w, h=m
  const uint4* xf4 = reinterpret_cast<const uint4*>(xbf);
  uint4 afr[16];
#pragma unroll
  for (int m = 0; m < 2; ++m)
#pragma unroll
    for (int kb = 0; kb < 8; ++kb)
      afr[m * 8 + kb] =
          xf4[((size_t)((rowblk * 8 + w) * 8 + kb) * 2 + m) * 64 + l];

  uint32_t v[6];
#pragma unroll
  for (int j = 0; j < 6; ++j) v[j] = 0xFFFFFFFFu;
  const int srowL = w * 32 + (l >> 1);  // this thread's scan row (own wave)
  const int shalf = l & 1;

  const char* xb = reinterpret_cast<const char*>(xbf);
  // prologue: stage tile 0 (contiguous 16KB, 2 rounds x 512 x 16B)
#pragma unroll
  for (int i = 0; i < 2; ++i) {
    int p = i * 512 + tid;
    gload_lds16(xb + (size_t)(chunk * 8) * 16384 + p * 16, smem + p * 16);
  }
  __syncthreads();

  int buf = 0;
  for (int tc = 0; tc < 8; ++tc) {
    if (tc < 7) {
#pragma unroll
      for (int i = 0; i < 2; ++i) {
        int p = i * 512 + tid;
        gload_lds16(xb + (size_t)(chunk * 8 + tc + 1) * 16384 + p * 16,
                    smem + (buf ^ 1) * 16384 + p * 16);
      }
    }
    float sqjq0 = sq[colbase + tc * 32 + c] * 0.25f;
    float sqjq1 = sq[colbase + tc * 32 + 16 + c] * 0.25f;

    f32x4 acc[2][2];
#pragma unroll
    for (int m = 0; m < 2; ++m)
#pragma unroll
      for (int n = 0; n < 2; ++n) acc[m][n] = (f32x4){0.f, 0.f, 0.f, 0.f};

    const char* Bb = smem + buf * 16384;
#pragma unroll
    for (int kb = 0; kb < 8; ++kb) {
      bf16x8 b0 = *reinterpret_cast<const bf16x8*>(Bb + kb * 2048 + l * 16);
      bf16x8 b1 = *reinterpret_cast<const bf16x8*>(Bb + kb * 2048 + 1024 + l * 16);
#pragma unroll
      for (int m = 0; m < 2; ++m) {
        bf16x8 av = __builtin_bit_cast(bf16x8, afr[m * 8 + kb]);
        acc[m][0] = __builtin_amdgcn_mfma_f32_16x16x32_bf16(av, b0, acc[m][0], 0, 0, 0);
        acc[m][1] = __builtin_amdgcn_mfma_f32_16x16x32_bf16(av, b1, acc[m][1], 0, 0, 0);
      }
    }
    // epilogue: pk key pairs -> skeys[c*257 + row_local] (own-wave rows)
    {
      const uint32_t meta = (uint32_t)((tc << 4) | c);
      uint32_t* sk = skeys + c * 257 + w * 32 + g * 4;
#pragma unroll
      for (int m = 0; m < 2; ++m)
#pragma unroll
        for (int e = 0; e < 4; ++e) {
          float a0 = fmaf(acc[m][0][e], -0.5f, sqjq0);
          float a1 = fmaf(acc[m][1][e], -0.5f, sqjq1);
          uint32_t k0 = ((uint32_t)fmaxf(a0, 0.0f) << 8) | meta;
          uint32_t k1 = ((uint32_t)fmaxf(a1, 0.0f) << 8) | meta;
          uint32_t pk = (umin32(k1, 65535u) << 16) | umin32(k0, 65535u);
          sk[m * 16 + e] = pk;
        }
    }
    // scan: lane pair (2k,2k+1) owns row w*32+k, halves of c-range;
    // writes+reads are same-wave -> in-order, no barrier needed.
#pragma unroll
    for (int u = 0; u < 8; ++u) {
      uint32_t t = skeys[(shalf * 8 + u) * 257 + srowL];
#pragma unroll
      for (int j = 0; j < 6; ++j) {
        uint32_t vj = v[j];
        v[j] = pkmin16(vj, t);
        t    = pkmax16(vj, t);
      }
    }
    __syncthreads();   // B-buffer swap (drains global_load_lds of tc+1)
    buf ^= 1;
  }
  // unpack 12 keys -> u32 (q<<9)|(tc<<5)|(n<<4)|c, exact within this half
  uint32_t fin[6];
#pragma unroll
  for (int j = 0; j < 6; ++j) fin[j] = 0xFFFFFFFFu;
#pragma unroll
  for (int j = 0; j < 6; ++j) {
    uint32_t p = v[j];
#pragma unroll
    for (int h = 0; h < 2; ++h) {
      uint32_t k16 = (h ? (p >> 16) : p) & 0xFFFFu;
      uint32_t ku = ((k16 >> 8) << 9) | ((k16 & 0xF0u) << 1) |
                    ((uint32_t)h << 4) | (k16 & 0xFu);
#pragma unroll
      for (int q = 0; q < 6; ++q) {
        uint32_t fq = fin[q];
        fin[q] = umin32(fq, ku);
        ku     = umax32(fq, ku);
      }
    }
  }
  // merge the two halves of each row (lane pair) -> exact chunk top-6
  uint32_t oth[6];
#pragma unroll
  for (int j = 0; j < 6; ++j) oth[j] = __shfl_xor(fin[j], 1);
#pragma unroll
  for (int j = 0; j < 6; ++j) {
    uint32_t t = oth[j];
#pragma unroll
    for (int q = 0; q < 6; ++q) {
      uint32_t fq = fin[q];
      fin[q] = umin32(fq, t);
      t      = umax32(fq, t);
    }
  }
  if (shalf == 0) {
#pragma unroll
    for (int j = 0; j < 6; ++j) {
      uint32_t k = fin[j];
      cand[(size_t)(rowbase + srowL) * 192 + chunk * 6 + j] =
          ((k >> 9) << 13) | (uint32_t)colbase | (k & 0xFFu);
    }
  }
}

// ------------------------ kernel 3: rescore + emit -------------------------
// One wave per row: select 16 smallest of 192 packed keys; fp32 rescore with
// 4-lane groups (lane = 4*cand + dq); shfl_xor reduce; top-6 lex; PRNG; emit.
__global__ __launch_bounds__(256)
void rescore_emit_kernel(const float* __restrict__ x,
                         const float* __restrict__ sq,
                         const uint32_t* __restrict__ cand,
                         float* __restrict__ out) {
  const int tid = threadIdx.x;
  const int wid = tid >> 6;
  const int l   = tid & 63;
  const int row = blockIdx.x * 4 + wid;

  uint32_t k0 = cand[(size_t)row * 192 + l];
  uint32_t k1 = cand[(size_t)row * 192 + 64 + l];
  uint32_t k2 = cand[(size_t)row * 192 + 128 + l];
  int mycol = row;
#pragma unroll
  for (int it = 0; it < 16; ++it) {
    uint32_t mv = umin32(k0, umin32(k1, k2));
#pragma unroll
    for (int off = 1; off < 64; off <<= 1) {
      uint32_t o = __shfl_xor(mv, off);
      mv = umin32(mv, o);
    }
    if (l == it) mycol = (int)(mv & 8191u);
    if (k0 == mv) k0 = 0xFFFFFFFFu;
    else if (k1 == mv) k1 = 0xFFFFFFFFu;
    else if (k2 == mv) k2 = 0xFFFFFFFFu;
  }

  // fp32 rescore: 4-lane group per candidate; d4 = 4*i + dq
  const float4* x4 = reinterpret_cast<const float4*>(x);
  const int jg = l >> 2, dq = l & 3;
  const int cj = __shfl(mycol, jg);
  float acc = 0.0f;
#pragma unroll 4
  for (int i = 0; i < 16; ++i) {
    int d4 = i * 4 + dq;
    float4 a = x4[(size_t)row * 64 + d4];
    float4 b = x4[(size_t)cj * 64 + d4];
    acc = fmaf(a.x, b.x, acc);
    acc = fmaf(a.y, b.y, acc);
    acc = fmaf(a.z, b.z, acc);
    acc = fmaf(a.w, b.w, acc);
  }
  acc += __shfl_xor(acc, 1);
  acc += __shfl_xor(acc, 2);
  float myscore = sq[row] + sq[cj] - 2.0f * acc;   // valid on all 4 group lanes

  float v6[6]; int i6[6];
#pragma unroll
  for (int j = 0; j < 6; ++j) { v6[j] = 3.402823466e38f; i6[j] = 0x7fffffff; }
#pragma unroll
  for (int j = 0; j < 16; ++j) {
    float scj = __shfl(myscore, j * 4);
    int   ccj = __shfl(mycol, j);
    insert6(scj, ccj, v6, i6);
  }

  // PRNG: only the 3 per-row ciphers at runtime (keys are constexpr)
  uint32_t ri = (uint32_t)row;
  uint32_t h0 = 0, h1 = ri; tf2x32(K1.x, K1.y, h0, h1); uint32_t hb = h0 ^ h1;
  uint32_t l0 = 0, l1 = ri; tf2x32(K2.x, K2.y, l0, l1); uint32_t lb = l0 ^ l1;
  uint32_t u0 = 0, u1 = ri; tf2x32(KA.x, KA.y, u0, u1); uint32_t ub = u0 ^ u1;

  uint32_t ch = (hb % 5u + lb % 5u) % 5u;
  float al = __uint_as_float((ub >> 9) | 0x3F800000u) - 1.0f;
  al = fmaxf(0.0f, al);

  int sl = i6[1];
  sl = (ch == 1u) ? i6[2] : sl;
  sl = (ch == 2u) ? i6[3] : sl;
  sl = (ch == 3u) ? i6[4] : sl;
  sl = (ch == 4u) ? i6[5] : sl;

  // emit: copy row + augmented row (mul/mul/add, no FMA contraction)
  float4 xi = x4[(size_t)row * 64 + l];
  float4 xs = x4[(size_t)sl * 64 + l];
  float om = 1.0f - al;
  float4 o;
  o.x = __fadd_rn(__fmul_rn(om, xi.x), __fmul_rn(al, xs.x));
  o.y = __fadd_rn(__fmul_rn(om, xi.y), __fmul_rn(al, xs.y));
  o.z = __fadd_rn(__fmul_rn(om, xi.z), __fmul_rn(al, xs.z));
  o.w = __fadd_rn(__fmul_rn(om, xi.w), __fmul_rn(al, xs.w));
  float4* out4 = reinterpret_cast<float4*>(out);
  out4[(size_t)row * 64 + l] = xi;
  out4[(size_t)(NROWS + row) * 64 + l] = o;
}

// ------------------------------- launcher ----------------------------------
extern "C" void kernel_launch(void* const* d_in, const int* in_sizes, int n_in,
                              void* d_out, int out_size, void* d_ws, size_t ws_size,
                              hipStream_t stream) {
  const float* x = (const float*)d_in[0];
  float* out = (float*)d_out;
  char* ws = (char*)d_ws;

  // ws layout: sq (32KB) | xbf (4MB, fragment-linear) | cand (6.29MB)
  float* sq = (float*)ws;
  unsigned short* xbf = (unsigned short*)(ws + 32768);
  uint32_t* cand = (uint32_t*)(ws + 32768 + 4194304);

  hipLaunchKernelGGL(prep_kernel,         dim3(2048), dim3(256), 0, stream, x, sq, xbf);
  hipLaunchKernelGGL(gemm_topk_kernel,    dim3(1024), dim3(512), 0, stream, xbf, sq, cand);
  hipLaunchKernelGGL(rescore_emit_kernel, dim3(2048), dim3(256), 0, stream, x, sq, cand, out);
}

// Round 17
// 75.010 us; speedup vs baseline: 1.7324x; 1.7324x over previous
//
#include <hip/hip_runtime.h>
#include <stdint.h>

// ---------------------------------------------------------------------------
// ManifoldAugmentation: x (8192,256) fp32 ->
//   out = concat([x, (1-alpha)*x + alpha*x[sel]]) (16384,256) fp32
// Stage 1: bf16 MFMA GEMM, fragment-linear xbf (r12-proven), m=2 / 512 thr,
//          wave-local scan, single-buffer skeys, 256-col chunks, grid 1024
//          -> 3 blocks/CU resident under launch_bounds(512,4) (r16 fix:
//          (512,6) capped VGPR at 40 and spilled to scratch). 192 cand/row.
// Stage 2: fp32 rescore of top-16 of 192 (4-lane-group coalesced dot),
//          constexpr threefry key folding.
// PRNG: JAX threefry, partitionable semantics (verified PASS rounds 4-16).
// ---------------------------------------------------------------------------

#define NROWS 8192
#define ND4   64

typedef __attribute__((ext_vector_type(8))) short bf16x8;
typedef __attribute__((ext_vector_type(4))) float f32x4;

__device__ __forceinline__ uint32_t umin32(uint32_t a, uint32_t b) { return a < b ? a : b; }
__device__ __forceinline__ uint32_t umax32(uint32_t a, uint32_t b) { return a > b ? a : b; }

__device__ __forceinline__ uint32_t pkmin16(uint32_t a, uint32_t b) {
  uint32_t r;
  asm("v_pk_min_u16 %0, %1, %2" : "=v"(r) : "v"(a), "v"(b));
  return r;
}
__device__ __forceinline__ uint32_t pkmax16(uint32_t a, uint32_t b) {
  uint32_t r;
  asm("v_pk_max_u16 %0, %1, %2" : "=v"(r) : "v"(a), "v"(b));
  return r;
}

// ------------------------- threefry2x32 (20 rounds) ------------------------
__device__ __forceinline__ uint32_t rotl32(uint32_t v, int d) {
  return (v << d) | (v >> (32 - d));
}

#define TFBODY(k0, k1)                                                        \
  const uint32_t ks2 = (k0) ^ (k1) ^ 0x1BD11BDAu;                             \
  x0 += (k0); x1 += (k1);                                                     \
  TFR(13) TFR(15) TFR(26) TFR(6)                                              \
  x0 += (k1);  x1 += ks2 + 1u;                                                \
  TFR(17) TFR(29) TFR(16) TFR(24)                                             \
  x0 += ks2; x1 += (k0) + 2u;                                                 \
  TFR(13) TFR(15) TFR(26) TFR(6)                                              \
  x0 += (k0);  x1 += (k1) + 3u;                                               \
  TFR(17) TFR(29) TFR(16) TFR(24)                                             \
  x0 += (k1);  x1 += ks2 + 4u;                                                \
  TFR(13) TFR(15) TFR(26) TFR(6)                                              \
  x0 += ks2; x1 += (k0) + 5u;

__device__ __forceinline__ void tf2x32(uint32_t k0, uint32_t k1,
                                       uint32_t& x0, uint32_t& x1) {
#define TFR(R) { x0 += x1; x1 = rotl32(x1, R); x1 ^= x0; }
  TFBODY(k0, k1)
#undef TFR
}

// compile-time threefry (identical math) for constant key derivation
struct U2 { uint32_t x, y; };
constexpr uint32_t crotl(uint32_t v, int d) {
  return (v << d) | (v >> (32 - d));
}
constexpr U2 tfc(uint32_t k0, uint32_t k1, uint32_t x0, uint32_t x1) {
#define TFR(R) { x0 += x1; x1 = crotl(x1, R); x1 ^= x0; }
  TFBODY(k0, k1)
#undef TFR
  return U2{x0, x1};
}
// rng = fold_in(key(42),0); kc,ka = split(rng); k1,k2 = split(kc)
constexpr U2 RG = tfc(0u, 42u, 0u, 0u);
constexpr U2 KC = tfc(RG.x, RG.y, 0u, 0u);
constexpr U2 KA = tfc(RG.x, RG.y, 0u, 1u);
constexpr U2 K1 = tfc(KC.x, KC.y, 0u, 0u);
constexpr U2 K2 = tfc(KC.x, KC.y, 0u, 1u);

// --------------------- top-6 (val,idx) lexicographic (fp32 stage) ----------
__device__ __forceinline__ bool lessp(float a, int ai, float b, int bi) {
  return (a < b) || ((a == b) && (ai < bi));
}

__device__ __forceinline__ void insert6(float key, int idx,
                                        float (&v)[6], int (&ix)[6]) {
  if (!lessp(key, idx, v[5], ix[5])) return;
#pragma unroll
  for (int j = 5; j >= 1; --j) {
    if (lessp(key, idx, v[j - 1], ix[j - 1])) {
      v[j] = v[j - 1]; ix[j] = ix[j - 1];
    } else {
      v[j] = key; ix[j] = idx; return;
    }
  }
  v[0] = key; ix[0] = idx;
}

// ----------------------------- small helpers -------------------------------
__device__ __forceinline__ unsigned short f2bf(float f) {
  uint32_t u = __float_as_uint(f);
  u += 0x7FFFu + ((u >> 16) & 1u);          // RNE
  return (unsigned short)(u >> 16);
}

__device__ __forceinline__ void gload_lds16(const void* g, void* l) {
  __builtin_amdgcn_global_load_lds(
      (const __attribute__((address_space(1))) unsigned int*)g,
      (__attribute__((address_space(3))) unsigned int*)l, 16, 0, 0);
}

// ------------------------------ kernel 1: prep -----------------------------
// sq (round-4 exact reduce) + bf16 convert into FRAGMENT-LINEAR layout (r12).
__global__ void prep_kernel(const float* __restrict__ x,
                            float* __restrict__ sq,
                            unsigned short* __restrict__ xbf) {
  int row  = blockIdx.x * 4 + (threadIdx.x >> 6);
  int lane = threadIdx.x & 63;
  const float4* xv4 = reinterpret_cast<const float4*>(x);
  float4 vv = xv4[(size_t)row * ND4 + lane];
  float t = vv.x * vv.x + vv.y * vv.y + vv.z * vv.z + vv.w * vv.w;
#pragma unroll
  for (int off = 32; off >= 1; off >>= 1) t += __shfl_down(t, off);
  if (lane == 0) sq[row] = t;
  ushort4 st;
  st.x = f2bf(vv.x); st.y = f2bf(vv.y); st.z = f2bf(vv.z); st.w = f2bf(vv.w);
  int T = row >> 5, h = (row >> 4) & 1, c = row & 15;
  int kb = lane >> 3, g = (lane >> 1) & 3, half8 = lane & 1;
  size_t f = ((size_t)(T * 8 + kb) * 2 + h) * 64 + g * 16 + c;
  *reinterpret_cast<ushort4*>(xbf + f * 8 + half8 * 4) = st;
}

// --------------------------- kernel 2: gemm+topk ---------------------------
// grid 1024 = 32 row-blocks (256 rows) x 32 col-chunks (256 cols); 512 thr.
// 8 waves x 32-row stripes (m=2); B-tile (32 cols, 16KB) contiguous-staged,
// double-buffered; B ds_read_b128 lane-linear. skeys single-buffered: wave w
// writes AND scans its own rows (lane-pair per row) -> no barrier on skeys;
// one barrier/tile for the B buffer. v_pk sorted-6; end: unpack + lane-pair
// merge -> exact per-(row,chunk) top-6 -> 192 cand/row.
// LDS 49216B -> 3 blocks/CU; VGPR ~60 -> 8 waves/SIMD OK; grid 1024 feeds 3.
__global__ __launch_bounds__(512, 4)
void gemm_topk_kernel(const unsigned short* __restrict__ xbf,
                      const float* __restrict__ sq,
                      uint32_t* __restrict__ cand) {
  __shared__ __align__(16) char smem[49216];  // 2x16KB B + 16448B skeys
  uint32_t* skeys = reinterpret_cast<uint32_t*>(smem + 32768);

  const int tid = threadIdx.x;
  const int bid = blockIdx.x;
  const int rowblk = bid & 31;
  const int chunk  = bid >> 5;          // 0..31
  const int rowbase = rowblk * 256;
  const int colbase = chunk * 256;
  const int w = tid >> 6;
  const int l = tid & 63;
  const int g = l >> 4;
  const int c = l & 15;

  // A fragments: rows rowbase + w*32 + m*16 + c -> T=rowblk*8+w, h=m
  const uint4* xf4 = reinterpret_cast<const uint4*>(xbf);
  uint4 afr[16];
#pragma unroll
  for (int m = 0; m < 2; ++m)
#pragma unroll
    for (int kb = 0; kb < 8; ++kb)
      afr[m * 8 + kb] =
          xf4[((size_t)((rowblk * 8 + w) * 8 + kb) * 2 + m) * 64 + l];

  uint32_t v[6];
#pragma unroll
  for (int j = 0; j < 6; ++j) v[j] = 0xFFFFFFFFu;
  const int srowL = w * 32 + (l >> 1);  // this thread's scan row (own wave)
  const int shalf = l & 1;

  const char* xb = reinterpret_cast<const char*>(xbf);
  // prologue: stage tile 0 (contiguous 16KB, 2 rounds x 512 x 16B)
#pragma unroll
  for (int i = 0; i < 2; ++i) {
    int p = i * 512 + tid;
    gload_lds16(xb + (size_t)(chunk * 8) * 16384 + p * 16, smem + p * 16);
  }
  __syncthreads();

  int buf = 0;
  for (int tc = 0; tc < 8; ++tc) {
    if (tc < 7) {
#pragma unroll
      for (int i = 0; i < 2; ++i) {
        int p = i * 512 + tid;
        gload_lds16(xb + (size_t)(chunk * 8 + tc + 1) * 16384 + p * 16,
                    smem + (buf ^ 1) * 16384 + p * 16);
      }
    }
    float sqjq0 = sq[colbase + tc * 32 + c] * 0.25f;
    float sqjq1 = sq[colbase + tc * 32 + 16 + c] * 0.25f;

    f32x4 acc[2][2];
#pragma unroll
    for (int m = 0; m < 2; ++m)
#pragma unroll
      for (int n = 0; n < 2; ++n) acc[m][n] = (f32x4){0.f, 0.f, 0.f, 0.f};

    const char* Bb = smem + buf * 16384;
#pragma unroll
    for (int kb = 0; kb < 8; ++kb) {
      bf16x8 b0 = *reinterpret_cast<const bf16x8*>(Bb + kb * 2048 + l * 16);
      bf16x8 b1 = *reinterpret_cast<const bf16x8*>(Bb + kb * 2048 + 1024 + l * 16);
#pragma unroll
      for (int m = 0; m < 2; ++m) {
        bf16x8 av = __builtin_bit_cast(bf16x8, afr[m * 8 + kb]);
        acc[m][0] = __builtin_amdgcn_mfma_f32_16x16x32_bf16(av, b0, acc[m][0], 0, 0, 0);
        acc[m][1] = __builtin_amdgcn_mfma_f32_16x16x32_bf16(av, b1, acc[m][1], 0, 0, 0);
      }
    }
    // epilogue: pk key pairs -> skeys[c*257 + row_local] (own-wave rows)
    {
      const uint32_t meta = (uint32_t)((tc << 4) | c);
      uint32_t* sk = skeys + c * 257 + w * 32 + g * 4;
#pragma unroll
      for (int m = 0; m < 2; ++m)
#pragma unroll
        for (int e = 0; e < 4; ++e) {
          float a0 = fmaf(acc[m][0][e], -0.5f, sqjq0);
          float a1 = fmaf(acc[m][1][e], -0.5f, sqjq1);
          uint32_t k0 = ((uint32_t)fmaxf(a0, 0.0f) << 8) | meta;
          uint32_t k1 = ((uint32_t)fmaxf(a1, 0.0f) << 8) | meta;
          uint32_t pk = (umin32(k1, 65535u) << 16) | umin32(k0, 65535u);
          sk[m * 16 + e] = pk;
        }
    }
    // scan: lane pair (2k,2k+1) owns row w*32+k, halves of c-range;
    // writes+reads are same-wave -> in-order, no barrier needed.
#pragma unroll
    for (int u = 0; u < 8; ++u) {
      uint32_t t = skeys[(shalf * 8 + u) * 257 + srowL];
#pragma unroll
      for (int j = 0; j < 6; ++j) {
        uint32_t vj = v[j];
        v[j] = pkmin16(vj, t);
        t    = pkmax16(vj, t);
      }
    }
    __syncthreads();   // B-buffer swap (drains global_load_lds of tc+1)
    buf ^= 1;
  }
  // unpack 12 keys -> u32 (q<<9)|(tc<<5)|(n<<4)|c, exact within this half
  uint32_t fin[6];
#pragma unroll
  for (int j = 0; j < 6; ++j) fin[j] = 0xFFFFFFFFu;
#pragma unroll
  for (int j = 0; j < 6; ++j) {
    uint32_t p = v[j];
#pragma unroll
    for (int h = 0; h < 2; ++h) {
      uint32_t k16 = (h ? (p >> 16) : p) & 0xFFFFu;
      uint32_t ku = ((k16 >> 8) << 9) | ((k16 & 0xF0u) << 1) |
                    ((uint32_t)h << 4) | (k16 & 0xFu);
#pragma unroll
      for (int q = 0; q < 6; ++q) {
        uint32_t fq = fin[q];
        fin[q] = umin32(fq, ku);
        ku     = umax32(fq, ku);
      }
    }
  }
  // merge the two halves of each row (lane pair) -> exact chunk top-6
  uint32_t oth[6];
#pragma unroll
  for (int j = 0; j < 6; ++j) oth[j] = __shfl_xor(fin[j], 1);
#pragma unroll
  for (int j = 0; j < 6; ++j) {
    uint32_t t = oth[j];
#pragma unroll
    for (int q = 0; q < 6; ++q) {
      uint32_t fq = fin[q];
      fin[q] = umin32(fq, t);
      t      = umax32(fq, t);
    }
  }
  if (shalf == 0) {
#pragma unroll
    for (int j = 0; j < 6; ++j) {
      uint32_t k = fin[j];
      cand[(size_t)(rowbase + srowL) * 192 + chunk * 6 + j] =
          ((k >> 9) << 13) | (uint32_t)colbase | (k & 0xFFu);
    }
  }
}

// ------------------------ kernel 3: rescore + emit -------------------------
// One wave per row: select 16 smallest of 192 packed keys; fp32 rescore with
// 4-lane groups (lane = 4*cand + dq); shfl_xor reduce; top-6 lex; PRNG; emit.
__global__ __launch_bounds__(256)
void rescore_emit_kernel(const float* __restrict__ x,
                         const float* __restrict__ sq,
                         const uint32_t* __restrict__ cand,
                         float* __restrict__ out) {
  const int tid = threadIdx.x;
  const int wid = tid >> 6;
  const int l   = tid & 63;
  const int row = blockIdx.x * 4 + wid;

  uint32_t k0 = cand[(size_t)row * 192 + l];
  uint32_t k1 = cand[(size_t)row * 192 + 64 + l];
  uint32_t k2 = cand[(size_t)row * 192 + 128 + l];
  int mycol = row;
#pragma unroll
  for (int it = 0; it < 16; ++it) {
    uint32_t mv = umin32(k0, umin32(k1, k2));
#pragma unroll
    for (int off = 1; off < 64; off <<= 1) {
      uint32_t o = __shfl_xor(mv, off);
      mv = umin32(mv, o);
    }
    if (l == it) mycol = (int)(mv & 8191u);
    if (k0 == mv) k0 = 0xFFFFFFFFu;
    else if (k1 == mv) k1 = 0xFFFFFFFFu;
    else if (k2 == mv) k2 = 0xFFFFFFFFu;
  }

  // fp32 rescore: 4-lane group per candidate; d4 = 4*i + dq
  const float4* x4 = reinterpret_cast<const float4*>(x);
  const int jg = l >> 2, dq = l & 3;
  const int cj = __shfl(mycol, jg);
  float acc = 0.0f;
#pragma unroll 4
  for (int i = 0; i < 16; ++i) {
    int d4 = i * 4 + dq;
    float4 a = x4[(size_t)row * 64 + d4];
    float4 b = x4[(size_t)cj * 64 + d4];
    acc = fmaf(a.x, b.x, acc);
    acc = fmaf(a.y, b.y, acc);
    acc = fmaf(a.z, b.z, acc);
    acc = fmaf(a.w, b.w, acc);
  }
  acc += __shfl_xor(acc, 1);
  acc += __shfl_xor(acc, 2);
  float myscore = sq[row] + sq[cj] - 2.0f * acc;   // valid on all 4 group lanes

  float v6[6]; int i6[6];
#pragma unroll
  for (int j = 0; j < 6; ++j) { v6[j] = 3.402823466e38f; i6[j] = 0x7fffffff; }
#pragma unroll
  for (int j = 0; j < 16; ++j) {
    float scj = __shfl(myscore, j * 4);
    int   ccj = __shfl(mycol, j);
    insert6(scj, ccj, v6, i6);
  }

  // PRNG: only the 3 per-row ciphers at runtime (keys are constexpr)
  uint32_t ri = (uint32_t)row;
  uint32_t h0 = 0, h1 = ri; tf2x32(K1.x, K1.y, h0, h1); uint32_t hb = h0 ^ h1;
  uint32_t l0 = 0, l1 = ri; tf2x32(K2.x, K2.y, l0, l1); uint32_t lb = l0 ^ l1;
  uint32_t u0 = 0, u1 = ri; tf2x32(KA.x, KA.y, u0, u1); uint32_t ub = u0 ^ u1;

  uint32_t ch = (hb % 5u + lb % 5u) % 5u;
  float al = __uint_as_float((ub >> 9) | 0x3F800000u) - 1.0f;
  al = fmaxf(0.0f, al);

  int sl = i6[1];
  sl = (ch == 1u) ? i6[2] : sl;
  sl = (ch == 2u) ? i6[3] : sl;
  sl = (ch == 3u) ? i6[4] : sl;
  sl = (ch == 4u) ? i6[5] : sl;

  // emit: copy row + augmented row (mul/mul/add, no FMA contraction)
  float4 xi = x4[(size_t)row * 64 + l];
  float4 xs = x4[(size_t)sl * 64 + l];
  float om = 1.0f - al;
  float4 o;
  o.x = __fadd_rn(__fmul_rn(om, xi.x), __fmul_rn(al, xs.x));
  o.y = __fadd_rn(__fmul_rn(om, xi.y), __fmul_rn(al, xs.y));
  o.z = __fadd_rn(__fmul_rn(om, xi.z), __fmul_rn(al, xs.z));
  o.w = __fadd_rn(__fmul_rn(om, xi.w), __fmul_rn(al, xs.w));
  float4* out4 = reinterpret_cast<float4*>(out);
  out4[(size_t)row * 64 + l] = xi;
  out4[(size_t)(NROWS + row) * 64 + l] = o;
}

// ------------------------------- launcher ----------------------------------
extern "C" void kernel_launch(void* const* d_in, const int* in_sizes, int n_in,
                              void* d_out, int out_size, void* d_ws, size_t ws_size,
                              hipStream_t stream) {
  const float* x = (const float*)d_in[0];
  float* out = (float*)d_out;
  char* ws = (char*)d_ws;

  // ws layout: sq (32KB) | xbf (4MB, fragment-linear) | cand (6.29MB)
  float* sq = (float*)ws;
  unsigned short* xbf = (unsigned short*)(ws + 32768);
  uint32_t* cand = (uint32_t*)(ws + 32768 + 4194304);

  hipLaunchKernelGGL(prep_kernel,         dim3(2048), dim3(256), 0, stream, x, sq, xbf);
  hipLaunchKernelGGL(gemm_topk_kernel,    dim3(1024), dim3(512), 0, stream, xbf, sq, cand);
  hipLaunchKernelGGL(rescore_emit_kernel, dim3(2048), dim3(256), 0, stream, x, sq, cand, out);
}

// Round 18
// 72.557 us; speedup vs baseline: 1.7909x; 1.0338x over previous
//
#include <hip/hip_runtime.h>
#include <stdint.h>

// ---------------------------------------------------------------------------
// ManifoldAugmentation: x (8192,256) fp32 ->
//   out = concat([x, (1-alpha)*x + alpha*x[sel]]) (16384,256) fp32
// FINAL (= round-12 best measured: 73.1 us total, gemm 48.7 us):
// Stage 1: bf16 MFMA GEMM on FRAGMENT-LINEAR xbf (B-staging = contiguous
//          copy, B ds_read_b128 lane-linear conflict-free); row-relative
//          scores quantized to u16 key pairs; v_pk_min/max sorted-6 scan;
//          one barrier/tile; 192 cand/row.
// Stage 2: fp32 rescore of top-16 (4-lane-group coalesced dot, exact
//          reference summation order), constexpr threefry key folding.
// PRNG: JAX threefry, partitionable semantics (verified PASS rounds 4-17).
// ---------------------------------------------------------------------------

#define NROWS 8192
#define ND4   64

typedef __attribute__((ext_vector_type(8))) short bf16x8;
typedef __attribute__((ext_vector_type(4))) float f32x4;

__device__ __forceinline__ uint32_t umin32(uint32_t a, uint32_t b) { return a < b ? a : b; }
__device__ __forceinline__ uint32_t umax32(uint32_t a, uint32_t b) { return a > b ? a : b; }

__device__ __forceinline__ uint32_t pkmin16(uint32_t a, uint32_t b) {
  uint32_t r;
  asm("v_pk_min_u16 %0, %1, %2" : "=v"(r) : "v"(a), "v"(b));
  return r;
}
__device__ __forceinline__ uint32_t pkmax16(uint32_t a, uint32_t b) {
  uint32_t r;
  asm("v_pk_max_u16 %0, %1, %2" : "=v"(r) : "v"(a), "v"(b));
  return r;
}

// ------------------------- threefry2x32 (20 rounds) ------------------------
__device__ __forceinline__ uint32_t rotl32(uint32_t v, int d) {
  return (v << d) | (v >> (32 - d));
}

#define TFBODY(k0, k1)                                                        \
  const uint32_t ks2 = (k0) ^ (k1) ^ 0x1BD11BDAu;                             \
  x0 += (k0); x1 += (k1);                                                     \
  TFR(13) TFR(15) TFR(26) TFR(6)                                              \
  x0 += (k1);  x1 += ks2 + 1u;                                                \
  TFR(17) TFR(29) TFR(16) TFR(24)                                             \
  x0 += ks2; x1 += (k0) + 2u;                                                 \
  TFR(13) TFR(15) TFR(26) TFR(6)                                              \
  x0 += (k0);  x1 += (k1) + 3u;                                               \
  TFR(17) TFR(29) TFR(16) TFR(24)                                             \
  x0 += (k1);  x1 += ks2 + 4u;                                                \
  TFR(13) TFR(15) TFR(26) TFR(6)                                              \
  x0 += ks2; x1 += (k0) + 5u;

__device__ __forceinline__ void tf2x32(uint32_t k0, uint32_t k1,
                                       uint32_t& x0, uint32_t& x1) {
#define TFR(R) { x0 += x1; x1 = rotl32(x1, R); x1 ^= x0; }
  TFBODY(k0, k1)
#undef TFR
}

// compile-time threefry (identical math) for constant key derivation
struct U2 { uint32_t x, y; };
constexpr uint32_t crotl(uint32_t v, int d) {
  return (v << d) | (v >> (32 - d));
}
constexpr U2 tfc(uint32_t k0, uint32_t k1, uint32_t x0, uint32_t x1) {
#define TFR(R) { x0 += x1; x1 = crotl(x1, R); x1 ^= x0; }
  TFBODY(k0, k1)
#undef TFR
  return U2{x0, x1};
}
// rng = fold_in(key(42),0); kc,ka = split(rng); k1,k2 = split(kc)
constexpr U2 RG = tfc(0u, 42u, 0u, 0u);
constexpr U2 KC = tfc(RG.x, RG.y, 0u, 0u);
constexpr U2 KA = tfc(RG.x, RG.y, 0u, 1u);
constexpr U2 K1 = tfc(KC.x, KC.y, 0u, 0u);
constexpr U2 K2 = tfc(KC.x, KC.y, 0u, 1u);

// --------------------- top-6 (val,idx) lexicographic (fp32 stage) ----------
__device__ __forceinline__ bool lessp(float a, int ai, float b, int bi) {
  return (a < b) || ((a == b) && (ai < bi));
}

__device__ __forceinline__ void insert6(float key, int idx,
                                        float (&v)[6], int (&ix)[6]) {
  if (!lessp(key, idx, v[5], ix[5])) return;
#pragma unroll
  for (int j = 5; j >= 1; --j) {
    if (lessp(key, idx, v[j - 1], ix[j - 1])) {
      v[j] = v[j - 1]; ix[j] = ix[j - 1];
    } else {
      v[j] = key; ix[j] = idx; return;
    }
  }
  v[0] = key; ix[0] = idx;
}

// ----------------------------- small helpers -------------------------------
__device__ __forceinline__ unsigned short f2bf(float f) {
  uint32_t u = __float_as_uint(f);
  u += 0x7FFFu + ((u >> 16) & 1u);          // RNE
  return (unsigned short)(u >> 16);
}

__device__ __forceinline__ void gload_lds16(const void* g, void* l) {
  __builtin_amdgcn_global_load_lds(
      (const __attribute__((address_space(1))) unsigned int*)g,
      (__attribute__((address_space(3))) unsigned int*)l, 16, 0, 0);
}

// ------------------------------ kernel 1: prep -----------------------------
// sq (round-4 exact reduce) + bf16 convert into FRAGMENT-LINEAR layout:
// fragment (T=row/32, kb=ku/4, h=(row/16)&1, lane=g*16+c) holds rows
// T*32+h*16+c, elements (kb*4+g)*8..+8 — the exact 16B an MFMA lane consumes.
__global__ void prep_kernel(const float* __restrict__ x,
                            float* __restrict__ sq,
                            unsigned short* __restrict__ xbf) {
  int row  = blockIdx.x * 4 + (threadIdx.x >> 6);
  int lane = threadIdx.x & 63;
  const float4* xv4 = reinterpret_cast<const float4*>(x);
  float4 vv = xv4[(size_t)row * ND4 + lane];
  float t = vv.x * vv.x + vv.y * vv.y + vv.z * vv.z + vv.w * vv.w;
#pragma unroll
  for (int off = 32; off >= 1; off >>= 1) t += __shfl_down(t, off);
  if (lane == 0) sq[row] = t;
  ushort4 st;
  st.x = f2bf(vv.x); st.y = f2bf(vv.y); st.z = f2bf(vv.z); st.w = f2bf(vv.w);
  int T = row >> 5, h = (row >> 4) & 1, c = row & 15;
  int kb = lane >> 3, g = (lane >> 1) & 3, half8 = lane & 1;
  size_t f = ((size_t)(T * 8 + kb) * 2 + h) * 64 + g * 16 + c;
  *reinterpret_cast<ushort4*>(xbf + f * 8 + half8 * 4) = st;
}

// --------------------------- kernel 2: gemm+topk ---------------------------
// grid 512 = 32 row-blocks (256 rows) x 16 col-chunks (512 cols); 512 thr.
// 8 waves x 32-row stripes; A-frags = lane-consecutive uint4 loads; B-tile
// (16KB) staged as a CONTIGUOUS copy, double-buffered; B ds_read_b128 is
// lane-linear (conflict-free). Epilogue: row-relative score key16 pairs,
// v_pk sorted-6 scan. One barrier per tile. skeys double-buffered.
__global__ __launch_bounds__(512, 4)
void gemm_topk_kernel(const unsigned short* __restrict__ xbf,
                      const float* __restrict__ sq,
                      uint32_t* __restrict__ cand) {
  __shared__ __align__(16) char smem[65664];  // 2x16KB B + 2x16448B skeys
  uint32_t* skeys = reinterpret_cast<uint32_t*>(smem + 32768);

  const int tid = threadIdx.x;
  const int bid = blockIdx.x;
  const int rowblk = bid & 31;
  const int chunk  = bid >> 5;
  const int rowbase = rowblk * 256;
  const int colbase = chunk * 512;
  const int w = tid >> 6;
  const int l = tid & 63;
  const int c = l & 15;

  // A fragments (fragment-linear): f = ((T*8+kb)*2+m)*64 + l, T=rowblk*8+w
  const uint4* xf4 = reinterpret_cast<const uint4*>(xbf);
  uint4 afr[16];
#pragma unroll
  for (int m = 0; m < 2; ++m)
#pragma unroll
    for (int kb = 0; kb < 8; ++kb)
      afr[m * 8 + kb] =
          xf4[((size_t)((rowblk * 8 + w) * 8 + kb) * 2 + m) * 64 + l];

  uint32_t v[6];
#pragma unroll
  for (int j = 0; j < 6; ++j) v[j] = 0xFFFFFFFFu;
  const int srow = tid >> 1, shalf = tid & 1;

  const char* xb = reinterpret_cast<const char*>(xbf);
  // prologue: stage tile 0 (contiguous 16KB copy)
#pragma unroll
  for (int i = 0; i < 2; ++i) {
    int p = i * 512 + tid;
    gload_lds16(xb + (size_t)(chunk * 16) * 16384 + p * 16, smem + p * 16);
  }
  __syncthreads();

  int buf = 0, kbf = 0;
  for (int tc = 0; tc < 16; ++tc) {
    if (tc < 15) {
#pragma unroll
      for (int i = 0; i < 2; ++i) {
        int p = i * 512 + tid;
        gload_lds16(xb + (size_t)(chunk * 16 + tc + 1) * 16384 + p * 16,
                    smem + (buf ^ 1) * 16384 + p * 16);
      }
    }
    float sqjq0 = sq[colbase + tc * 32 + c] * 0.25f;
    float sqjq1 = sq[colbase + tc * 32 + 16 + c] * 0.25f;

    f32x4 acc[2][2];
#pragma unroll
    for (int m = 0; m < 2; ++m)
#pragma unroll
      for (int n = 0; n < 2; ++n) acc[m][n] = (f32x4){0.f, 0.f, 0.f, 0.f};

    const char* Bb = smem + buf * 16384;
#pragma unroll
    for (int kb = 0; kb < 8; ++kb) {
      bf16x8 b0 = *reinterpret_cast<const bf16x8*>(Bb + kb * 2048 + l * 16);
      bf16x8 b1 = *reinterpret_cast<const bf16x8*>(Bb + kb * 2048 + 1024 + l * 16);
#pragma unroll
      for (int m = 0; m < 2; ++m) {
        bf16x8 av = __builtin_bit_cast(bf16x8, afr[m * 8 + kb]);
        acc[m][0] = __builtin_amdgcn_mfma_f32_16x16x32_bf16(av, b0, acc[m][0], 0, 0, 0);
        acc[m][1] = __builtin_amdgcn_mfma_f32_16x16x32_bf16(av, b1, acc[m][1], 0, 0, 0);
      }
    }
    // epilogue: key16 pair -> skeys[kbf] (stride 257)
    {
      const int g = l >> 4;
      const uint32_t meta = (uint32_t)((tc << 4) | c);
      uint32_t* sk = skeys + kbf * 4112 + c * 257;
#pragma unroll
      for (int m = 0; m < 2; ++m)
#pragma unroll
        for (int e = 0; e < 4; ++e) {
          float a0 = fmaf(acc[m][0][e], -0.5f, sqjq0);
          float a1 = fmaf(acc[m][1][e], -0.5f, sqjq1);
          uint32_t k0 = ((uint32_t)fmaxf(a0, 0.0f) << 8) | meta;
          uint32_t k1 = ((uint32_t)fmaxf(a1, 0.0f) << 8) | meta;
          uint32_t pk = (umin32(k1, 65535u) << 16) | umin32(k0, 65535u);
          sk[w * 32 + m * 16 + g * 4 + e] = pk;
        }
    }
    __syncthreads();
    // scan: thread (srow, shalf) pk-bubbles its 8 packed values
    {
      const uint32_t* sk = skeys + kbf * 4112;
#pragma unroll
      for (int u = 0; u < 8; ++u) {
        uint32_t t = sk[(shalf * 8 + u) * 257 + srow];
#pragma unroll
        for (int j = 0; j < 6; ++j) {
          uint32_t vj = v[j];
          v[j] = pkmin16(vj, t);
          t    = pkmax16(vj, t);
        }
      }
    }
    buf ^= 1; kbf ^= 1;
  }
  // merge lo/hi quarters: unpack 12 keys -> u32 (q<<9)|(tc<<5)|(n<<4)|c
  uint32_t fin[6];
#pragma unroll
  for (int j = 0; j < 6; ++j) fin[j] = 0xFFFFFFFFu;
#pragma unroll
  for (int j = 0; j < 6; ++j) {
    uint32_t p = v[j];
#pragma unroll
    for (int h = 0; h < 2; ++h) {
      uint32_t k16 = (h ? (p >> 16) : p) & 0xFFFFu;
      uint32_t ku = ((k16 >> 8) << 9) | ((k16 & 0xF0u) << 1) |
                    ((uint32_t)h << 4) | (k16 & 0xFu);
#pragma unroll
      for (int q = 0; q < 6; ++q) {
        uint32_t fq = fin[q];
        fin[q] = umin32(fq, ku);
        ku     = umax32(fq, ku);
      }
    }
  }
#pragma unroll
  for (int j = 0; j < 6; ++j) {
    uint32_t k = fin[j];
    cand[(size_t)(rowbase + srow) * 192 + chunk * 12 + shalf * 6 + j] =
        ((k >> 9) << 13) | (uint32_t)colbase | (k & 0x1FFu);
  }
}

// ------------------------ kernel 3: rescore + emit -------------------------
// One wave per row: select 16 smallest of 192 packed keys; fp32 rescore with
// 4-lane groups (lane = 4*cand + dq): coalesced 64B group loads, each line
// fetched once; shfl_xor reduce; top-6 lex; PRNG (3 runtime ciphers); emit.
__global__ __launch_bounds__(256)
void rescore_emit_kernel(const float* __restrict__ x,
                         const float* __restrict__ sq,
                         const uint32_t* __restrict__ cand,
                         float* __restrict__ out) {
  const int tid = threadIdx.x;
  const int wid = tid >> 6;
  const int l   = tid & 63;
  const int row = blockIdx.x * 4 + wid;

  uint32_t k0 = cand[(size_t)row * 192 + l];
  uint32_t k1 = cand[(size_t)row * 192 + 64 + l];
  uint32_t k2 = cand[(size_t)row * 192 + 128 + l];
  int mycol = row;
#pragma unroll
  for (int it = 0; it < 16; ++it) {
    uint32_t mv = umin32(k0, umin32(k1, k2));
#pragma unroll
    for (int off = 1; off < 64; off <<= 1) {
      uint32_t o = __shfl_xor(mv, off);
      mv = umin32(mv, o);
    }
    if (l == it) mycol = (int)(mv & 8191u);
    if (k0 == mv) k0 = 0xFFFFFFFFu;
    else if (k1 == mv) k1 = 0xFFFFFFFFu;
    else if (k2 == mv) k2 = 0xFFFFFFFFu;
  }

  // fp32 rescore: 4-lane group per candidate; d4 = 4*i + dq
  const float4* x4 = reinterpret_cast<const float4*>(x);
  const int jg = l >> 2, dq = l & 3;
  const int cj = __shfl(mycol, jg);
  float acc = 0.0f;
#pragma unroll 4
  for (int i = 0; i < 16; ++i) {
    int d4 = i * 4 + dq;
    float4 a = x4[(size_t)row * 64 + d4];
    float4 b = x4[(size_t)cj * 64 + d4];
    acc = fmaf(a.x, b.x, acc);
    acc = fmaf(a.y, b.y, acc);
    acc = fmaf(a.z, b.z, acc);
    acc = fmaf(a.w, b.w, acc);
  }
  acc += __shfl_xor(acc, 1);
  acc += __shfl_xor(acc, 2);
  float myscore = sq[row] + sq[cj] - 2.0f * acc;   // valid on all 4 group lanes

  float v6[6]; int i6[6];
#pragma unroll
  for (int j = 0; j < 6; ++j) { v6[j] = 3.402823466e38f; i6[j] = 0x7fffffff; }
#pragma unroll
  for (int j = 0; j < 16; ++j) {
    float scj = __shfl(myscore, j * 4);
    int   ccj = __shfl(mycol, j);
    insert6(scj, ccj, v6, i6);
  }

  // PRNG: only the 3 per-row ciphers at runtime (keys are constexpr)
  uint32_t ri = (uint32_t)row;
  uint32_t h0 = 0, h1 = ri; tf2x32(K1.x, K1.y, h0, h1); uint32_t hb = h0 ^ h1;
  uint32_t l0 = 0, l1 = ri; tf2x32(K2.x, K2.y, l0, l1); uint32_t lb = l0 ^ l1;
  uint32_t u0 = 0, u1 = ri; tf2x32(KA.x, KA.y, u0, u1); uint32_t ub = u0 ^ u1;

  uint32_t ch = (hb % 5u + lb % 5u) % 5u;
  float al = __uint_as_float((ub >> 9) | 0x3F800000u) - 1.0f;
  al = fmaxf(0.0f, al);

  int sl = i6[1];
  sl = (ch == 1u) ? i6[2] : sl;
  sl = (ch == 2u) ? i6[3] : sl;
  sl = (ch == 3u) ? i6[4] : sl;
  sl = (ch == 4u) ? i6[5] : sl;

  // emit: copy row + augmented row (mul/mul/add, no FMA contraction)
  float4 xi = x4[(size_t)row * 64 + l];
  float4 xs = x4[(size_t)sl * 64 + l];
  float om = 1.0f - al;
  float4 o;
  o.x = __fadd_rn(__fmul_rn(om, xi.x), __fmul_rn(al, xs.x));
  o.y = __fadd_rn(__fmul_rn(om, xi.y), __fmul_rn(al, xs.y));
  o.z = __fadd_rn(__fmul_rn(om, xi.z), __fmul_rn(al, xs.z));
  o.w = __fadd_rn(__fmul_rn(om, xi.w), __fmul_rn(al, xs.w));
  float4* out4 = reinterpret_cast<float4*>(out);
  out4[(size_t)row * 64 + l] = xi;
  out4[(size_t)(NROWS + row) * 64 + l] = o;
}

// ------------------------------- launcher ----------------------------------
extern "C" void kernel_launch(void* const* d_in, const int* in_sizes, int n_in,
                              void* d_out, int out_size, void* d_ws, size_t ws_size,
                              hipStream_t stream) {
  const float* x = (const float*)d_in[0];
  float* out = (float*)d_out;
  char* ws = (char*)d_ws;

  // ws layout: sq (32KB) | xbf (4MB, fragment-linear) | cand (6.29MB)
  float* sq = (float*)ws;
  unsigned short* xbf = (unsigned short*)(ws + 32768);
  uint32_t* cand = (uint32_t*)(ws + 32768 + 4194304);

  hipLaunchKernelGGL(prep_kernel,         dim3(2048), dim3(256), 0, stream, x, sq, xbf);
  hipLaunchKernelGGL(gemm_topk_kernel,    dim3(512),  dim3(512), 0, stream, xbf, sq, cand);
  hipLaunchKernelGGL(rescore_emit_kernel, dim3(2048), dim3(256), 0, stream, x, sq, cand, out);
}